// Round 9
// baseline (316.909 us; speedup 1.0000x reference)
//
#include <hip/hip_runtime.h>
#include <hip/hip_bf16.h>

// Problem constants
#define BB 16
#define TT 512
#define KK 32
#define VV 512
#define DD 64
#define HH 128
#define KV (KK*VV)   // 16384
#define KKK (KK*KK)  // 1024

#define INV_LN2 1.4426950408889634f
#define LN2 0.6931471805599453f

typedef unsigned short u16;
typedef __attribute__((ext_vector_type(8))) short short8;
typedef __attribute__((ext_vector_type(8))) unsigned short ushort8;
typedef __attribute__((ext_vector_type(16))) float f32x16;
typedef __attribute__((ext_vector_type(4))) unsigned int uint4v;

__device__ __forceinline__ float fexp2(float x) { return __builtin_amdgcn_exp2f(x); }
__device__ __forceinline__ float flog2(float x) { return __builtin_amdgcn_logf(x); }

// float -> bf16 bits, round-nearest-even (finite inputs only)
__device__ __forceinline__ u16 f2bf(float f) {
  unsigned u = __builtin_bit_cast(unsigned, f);
  u += 0x7FFFu + ((u >> 16) & 1u);
  return (u16)(u >> 16);
}
__device__ __forceinline__ float bf2f(u16 v) {
  return __builtin_bit_cast(float, ((unsigned)v) << 16);
}

// 128-dim half-dot of two bf16 rows (64 elements each, this lane's half),
// 4 independent accumulators to break the serial FMA chain.
__device__ __forceinline__ float es_dot(const u16* __restrict__ erow,
                                        const u16* __restrict__ hrow) {
  float a0 = 0.f, a1 = 0.f, a2 = 0.f, a3 = 0.f;
#pragma unroll
  for (int r = 0; r < 8; ++r) {
    short8 ev = ((const short8*)erow)[r];
    short8 hv = ((const short8*)hrow)[r];
    a0 += bf2f((u16)ev[0]) * bf2f((u16)hv[0]);
    a1 += bf2f((u16)ev[1]) * bf2f((u16)hv[1]);
    a2 += bf2f((u16)ev[2]) * bf2f((u16)hv[2]);
    a3 += bf2f((u16)ev[3]) * bf2f((u16)hv[3]);
    a0 += bf2f((u16)ev[4]) * bf2f((u16)hv[4]);
    a1 += bf2f((u16)ev[5]) * bf2f((u16)hv[5]);
    a2 += bf2f((u16)ev[6]) * bf2f((u16)hv[6]);
    a3 += bf2f((u16)ev[7]) * bf2f((u16)hv[7]);
  }
  return (a0 + a1) + (a2 + a3);
}

// One step of the 32x32 matrix-chain product: D = A(fr0,fr1) x D.
// D layout: lane(l) col=l&31, rows (r&3)+8*(r>>2)+4*(l>>5).
__device__ __forceinline__ void mul_step(short8 fr0, short8 fr1, int h,
                                         float* D) {
  float e0[8], e1[8];
#pragma unroll
  for (int i2 = 0; i2 < 4; ++i2) {
    float x0 = __shfl_xor(D[i2], 32);
    float y0 = __shfl_xor(D[4 + i2], 32);
    e0[i2] = (h == 0) ? D[i2] : y0;
    e0[4 + i2] = (h == 0) ? x0 : D[4 + i2];
    float x1 = __shfl_xor(D[8 + i2], 32);
    float y1 = __shfl_xor(D[12 + i2], 32);
    e1[i2] = (h == 0) ? D[8 + i2] : y1;
    e1[4 + i2] = (h == 0) ? x1 : D[12 + i2];
  }
  short8 B0, B1;
#pragma unroll
  for (int e = 0; e < 8; ++e) {
    B0[e] = (short)f2bf(e0[e]);
    B1[e] = (short)f2bf(e1[e]);
  }
  f32x16 dn = {};
  dn = __builtin_amdgcn_mfma_f32_32x32x16_bf16(fr0, B0, dn, 0, 0, 0);
  dn = __builtin_amdgcn_mfma_f32_32x32x16_bf16(fr1, B1, dn, 0, 0, 0);
#pragma unroll
  for (int r = 0; r < 16; ++r) D[r] = dn[r];
}

__device__ __forceinline__ void ident_D(int j, int h, float* D) {
#pragma unroll
  for (int r = 0; r < 16; ++r) D[r] = 0.f;
  if (((j >> 2) & 1) == h) D[(j & 3) | ((j >> 3) << 2)] = 1.0f;
}

// ---------------------------------------------------------------------------
// K0: merged prep.
//  blocks [0,1024):    LDS-tiled transpose E2 (128x16384 f32) -> E2bT bf16
//  blocks [1024,1088): LDS-tiled transpose W2 (128x1024 f32)  -> W2T  bf16
//  blocks [1088,1120): hidden activations h1b/h2b (bf16), 16 tokens/block
__global__ __launch_bounds__(256) void k_prep1(
    const float* __restrict__ E2, u16* __restrict__ E2bT,
    const float* __restrict__ W2, u16* __restrict__ W2T,
    const float* __restrict__ emb, const float* __restrict__ W1,
    const float* __restrict__ b1, const float* __restrict__ E1,
    const float* __restrict__ e1, u16* __restrict__ h1b,
    u16* __restrict__ h2b) {
  __shared__ float tl[32][65];
  __shared__ float embs[16][64];
  int tid = threadIdx.x;
  int bid = blockIdx.x;

  if (bid < 1088) {
    // ---- transpose tile: 32 h x 64 col ----
    const float* src;
    u16* dst;
    size_t srcld;
    int c0, h0;
    if (bid < 1024) {
      c0 = (bid & 255) * 64;
      h0 = (bid >> 8) * 32;
      src = E2;
      dst = E2bT;
      srcld = KV;
    } else {
      int b2i = bid - 1024;
      c0 = (b2i & 15) * 64;
      h0 = (b2i >> 4) * 32;
      src = W2;
      dst = W2T;
      srcld = KKK;
    }
    int r = tid >> 6, c = tid & 63;
#pragma unroll
    for (int rr = 0; rr < 8; ++rr)
      tl[r * 8 + rr][c] = src[(size_t)(h0 + r * 8 + rr) * srcld + c0 + c];
    __syncthreads();
    int cw = tid >> 3, hb = tid & 7;
#pragma unroll
    for (int pass = 0; pass < 2; ++pass) {
      int cc = pass * 32 + cw;
      unsigned lo = (unsigned)f2bf(tl[hb * 4 + 0][cc]) |
                    ((unsigned)f2bf(tl[hb * 4 + 1][cc]) << 16);
      unsigned hi = (unsigned)f2bf(tl[hb * 4 + 2][cc]) |
                    ((unsigned)f2bf(tl[hb * 4 + 3][cc]) << 16);
      uint2 v;
      v.x = lo;
      v.y = hi;
      *(uint2*)(dst + (size_t)(c0 + cc) * HH + h0 + hb * 4) = v;
    }
    return;
  }

  // ---- hidden: 16 tokens ----
  int u0 = (bid - 1088) * 16;
#pragma unroll
  for (int it = 0; it < 4; ++it) {
    int idx = it * 256 + tid;
    embs[idx >> 6][idx & 63] = emb[u0 * DD + idx];
  }
  __syncthreads();
  int h = tid & 127, tl2 = tid >> 7;
  float b1v = b1[h], e1v = e1[h];
#pragma unroll
  for (int it = 0; it < 8; ++it) {
    int tok = it * 2 + tl2;
    float a1 = b1v, a2 = e1v;
#pragma unroll 8
    for (int d = 0; d < DD; ++d) {
      float xv = embs[tok][d];
      a1 += xv * W1[d * HH + h];
      a2 += xv * E1[d * HH + h];
    }
    h1b[(u0 + tok) * HH + h] = f2bf(fmaxf(a1, 0.f));
    h2b[(u0 + tok) * HH + h] = f2bf(fmaxf(a2, 0.f));
  }
}

// ---------------------------------------------------------------------------
// K1: merged tables kernel.
//  blocks [0,512):   emission GEMM via MFMA + fused LSE over V (no-max).
//  blocks [512,640): transition tables via MFMA + fused log2-softmax.
__global__ __launch_bounds__(256) void k_tables(
    const u16* __restrict__ h1b, const u16* __restrict__ W2T,
    const float* __restrict__ b2, float* __restrict__ ltrans,
    const u16* __restrict__ h2b, const u16* __restrict__ E2bT,
    const float* __restrict__ e2, float* __restrict__ lse2_tab) {
  __shared__ float ls[4 * 32];
  int bid = blockIdx.x;
  int tid = threadIdx.x;
  int w = tid >> 6, l = tid & 63;
  int h = l >> 5, j = l & 31;

  if (bid < 512) {
    // ---- emission LSE ----
    int k = bid & 31;
    int u0 = (bid >> 5) * 32;

    short8 A[8];
#pragma unroll
    for (int kh = 0; kh < 8; ++kh)
      A[kh] = *(const short8*)(h2b + (u0 + j) * HH + kh * 16 + h * 8);

    float s[16];
#pragma unroll
    for (int r = 0; r < 16; ++r) s[r] = 0.f;

#pragma unroll
    for (int c = 0; c < 4; ++c) {
      int ct = w * 4 + c;
      int col = k * 512 + ct * 32 + j;
      const u16* bp = E2bT + (size_t)col * HH + h * 8;
      f32x16 acc = {};
#pragma unroll
      for (int kh = 0; kh < 8; ++kh) {
        short8 Bf = *(const short8*)(bp + kh * 16);
        acc = __builtin_amdgcn_mfma_f32_32x32x16_bf16(A[kh], Bf, acc, 0, 0, 0);
      }
      float e2v = e2[col] * INV_LN2;
#pragma unroll
      for (int r = 0; r < 16; ++r) s[r] += fexp2(acc[r] * INV_LN2 + e2v);
    }
#pragma unroll
    for (int r = 0; r < 16; ++r) {
#pragma unroll
      for (int d = 1; d < 32; d <<= 1) s[r] += __shfl_xor(s[r], d);
    }
    if (j == 0) {
#pragma unroll
      for (int r = 0; r < 16; ++r) {
        int row = (r & 3) + 8 * (r >> 2) + 4 * h;
        ls[w * 32 + row] = s[r];
      }
    }
    __syncthreads();
    if (tid < 32) {
      float total = ls[tid] + ls[32 + tid] + ls[64 + tid] + ls[96 + tid];
      lse2_tab[(u0 + tid) * KK + k] = flog2(total);
    }
    return;
  }

  // ---- transition tables ----
  int t2 = bid - 512;
  int i = t2 & 31;
  int tt = (t2 >> 5) * 4 + w;
  int u0 = tt * 32;

  f32x16 acc = {};
#pragma unroll
  for (int kh = 0; kh < 8; ++kh) {
    short8 A = *(const short8*)(h1b + (u0 + j) * HH + kh * 16 + h * 8);
    short8 Bf = *(const short8*)(W2T + (i * 32 + j) * HH + kh * 16 + h * 8);
    acc = __builtin_amdgcn_mfma_f32_32x32x16_bf16(A, Bf, acc, 0, 0, 0);
  }
  float b2v = b2[i * 32 + j] * INV_LN2;
  float lgv[16], se[16];
#pragma unroll
  for (int r = 0; r < 16; ++r) {
    lgv[r] = acc[r] * INV_LN2 + b2v;
    se[r] = fexp2(lgv[r]);
  }
#pragma unroll
  for (int r = 0; r < 16; ++r) {
#pragma unroll
    for (int d = 1; d < 32; d <<= 1) se[r] += __shfl_xor(se[r], d);
  }
#pragma unroll
  for (int r = 0; r < 16; ++r) {
    int row = (r & 3) + 8 * (r >> 2) + 4 * h;
    ltrans[(u0 + row) * KKK + j * KK + i] = lgv[r] - flog2(se[r]);
  }
}

// ---------------------------------------------------------------------------
// K2: fully-fused scan: one block per batch (16 waves). Wave w owns steps
// [w*32, w*32+32) as 4 sub-chunks of 8: build fragments (es-dot gather +
// ltrans + normalize) then 8 chained MFMA muls, rescale, accumulate log2
// scale. Wave partials -> LDS (row stride 40 u16, 16B-aligned), one barrier,
// wave 0 chains the 16 partials + alpha0/es(t=0) epilogue -> out[b].
// No cross-block communication, no fences, no atomics.
#define MSTRIDE 40
__global__ __launch_bounds__(1024) void k_matfinal(
    const int* __restrict__ seq, const int* __restrict__ lengths,
    const float* __restrict__ ltrans, const u16* __restrict__ h2b,
    const u16* __restrict__ E2bT, const float* __restrict__ e2,
    const float* __restrict__ lse2, const float* __restrict__ init_logits,
    float* __restrict__ out) {
  __shared__ u16 mats[16][32 * MSTRIDE];
  __shared__ float scs[16];
  int b = blockIdx.x;
  int w = threadIdx.x >> 6, l = threadIdx.x & 63;
  int j = l & 31, h = l >> 5;
  int len = lengths[b];
  len = (len < 1) ? 1 : ((len > TT) ? TT : len);
  const int* sb = seq + b * TT;

  float D[16];
  ident_D(j, h, D);
  float wsc = 0.f;

#pragma unroll
  for (int sc = 0; sc < 4; ++sc) {
    int t0 = w * 32 + sc * 8;
    int clo = (t0 < 1) ? 1 : t0;
    int chi = (t0 + 8 < len) ? (t0 + 8) : len;
    if (clo >= chi) continue;  // fully identity sub-chunk (block-uniform len)

    // ---- Phase A: build 8 fragment pairs ----
    short8 fr0s[8], fr1s[8];
    float sacc = 0.f;
#pragma unroll
    for (int s = 0; s < 8; ++s) {
      int t = t0 + s;
      if (t >= 1 && t < len) {  // wave-uniform
        int u = sb[t - 1], y = sb[t];
        float dot = es_dot(E2bT + (size_t)(j * VV + y) * HH + h * 64,
                           h2b + u * HH + h * 64);
        dot += __shfl_xor(dot, 32);
        float esj = (dot + e2[j * VV + y]) * INV_LN2 - lse2[u * KK + j];
        float m = esj;  // scale = max_j esj (ltrans rows are <= 0)
#pragma unroll
        for (int d = 1; d < 32; d <<= 1) m = fmaxf(m, __shfl_xor(m, d));
        sacc += m;
        const float4* p4 = (const float4*)(ltrans + u * KKK + j * KK + h * 16);
        float4 q0 = p4[0], q1 = p4[1], q2 = p4[2], q3 = p4[3];
        float lgv[16] = {q0.x, q0.y, q0.z, q0.w, q1.x, q1.y, q1.z, q1.w,
                         q2.x, q2.y, q2.z, q2.w, q3.x, q3.y, q3.z, q3.w};
        float off = esj - m;
#pragma unroll
        for (int e = 0; e < 16; ++e) lgv[e] += off;
        unsigned pk[8];
#pragma unroll
        for (int p = 0; p < 8; ++p)
          pk[p] = (unsigned)f2bf(fexp2(lgv[2 * p])) |
                  ((unsigned)f2bf(fexp2(lgv[2 * p + 1])) << 16);
        unsigned rcv[4];
#pragma unroll
        for (int p = 0; p < 4; ++p)
          rcv[p] = (unsigned)__shfl_xor((int)(h == 0 ? pk[4 + p] : pk[p]), 32);
        unsigned f0[4], f1[4];
#pragma unroll
        for (int p = 0; p < 4; ++p) {
          f0[p] = h == 0 ? pk[p] : rcv[p];
          f1[p] = h == 0 ? rcv[p] : pk[4 + p];
        }
        fr0s[s] =
            __builtin_bit_cast(short8, (uint4v){f0[0], f0[1], f0[2], f0[3]});
        fr1s[s] =
            __builtin_bit_cast(short8, (uint4v){f1[0], f1[1], f1[2], f1[3]});
      } else {
        // identity A-fragment: fr0 covers k h*8+e, fr1 k 16+h*8+e
        ushort8 i0, i1;
#pragma unroll
        for (int e = 0; e < 8; ++e) {
          i0[e] = ((h * 8 + e) == j) ? (u16)0x3F80 : (u16)0;
          i1[e] = ((16 + h * 8 + e) == j) ? (u16)0x3F80 : (u16)0;
        }
        fr0s[s] = __builtin_bit_cast(short8, i0);
        fr1s[s] = __builtin_bit_cast(short8, i1);
      }
    }

    // ---- Phase B: chained product ----
#pragma unroll
    for (int s = 0; s < 8; ++s) mul_step(fr0s[s], fr1s[s], h, D);

    // ---- rescale to keep D in range; accumulate log2 scale ----
    float mx = D[0];
#pragma unroll
    for (int r = 1; r < 16; ++r) mx = fmaxf(mx, D[r]);
#pragma unroll
    for (int d = 1; d < 64; d <<= 1) mx = fmaxf(mx, __shfl_xor(mx, d));
    float inv = 1.0f / mx;
#pragma unroll
    for (int r = 0; r < 16; ++r) D[r] *= inv;
    wsc += flog2(mx) + sacc;
  }

  // write wave partial: mats[w][row][col], row-major, stride MSTRIDE u16
#pragma unroll
  for (int r = 0; r < 16; ++r) {
    int row = (r & 3) + 8 * (r >> 2) + 4 * h;
    mats[w][row * MSTRIDE + j] = f2bf(D[r]);
  }
  if (l == 0) scs[w] = wsc;
  __syncthreads();

  if (w == 0) {
    float D2[16];
    ident_D(j, h, D2);
#pragma unroll
    for (int s = 0; s < 16; ++s) {
      short8 fr0 = *(const short8*)(&mats[s][j * MSTRIDE + h * 8]);
      short8 fr1 = *(const short8*)(&mats[s][j * MSTRIDE + h * 8 + 16]);
      mul_step(fr0, fr1, h, D2);
    }
    // es(b, 0, j): input token at t=0 is the start token 0
    int y0 = seq[b * TT];
    float dot = es_dot(E2bT + (size_t)(j * VV + y0) * HH + h * 64,
                       h2b + h * 64);
    dot += __shfl_xor(dot, 32);
    float esj = (dot + e2[j * VV + y0]) * INV_LN2 - lse2[j];
    // alpha0 (log2 domain)
    float il = init_logits[j] * INV_LN2;
    float m0 = il;
#pragma unroll
    for (int d = 1; d < 32; d <<= 1) m0 = fmaxf(m0, __shfl_xor(m0, d));
    float s0 = fexp2(il - m0);
#pragma unroll
    for (int d = 1; d < 32; d <<= 1) s0 += __shfl_xor(s0, d);
    float lse0 = m0 + flog2(s0);
    float z = il - lse0 + esj;
    float am = z;
#pragma unroll
    for (int d = 1; d < 32; d <<= 1) am = fmaxf(am, __shfl_xor(am, d));
    float a0 = fexp2(z - am);
    float colsum = 0.f;
#pragma unroll
    for (int r = 0; r < 16; ++r) colsum += D2[r];
    float p = a0 * colsum;
#pragma unroll
    for (int d = 1; d < 64; d <<= 1) p += __shfl_xor(p, d);
    float sct = (l < 16) ? scs[l] : 0.f;
#pragma unroll
    for (int d = 1; d < 64; d <<= 1) sct += __shfl_xor(sct, d);
    if (l == 0) out[b] = -LN2 * (flog2(p) + am + sct);
  }
}

// ---------------------------------------------------------------------------
extern "C" void kernel_launch(void* const* d_in, const int* in_sizes, int n_in,
                              void* d_out, int out_size, void* d_ws,
                              size_t ws_size, hipStream_t stream) {
  const int* seq = (const int*)d_in[0];
  const int* lengths = (const int*)d_in[1];
  const float* emb = (const float*)d_in[2];
  const float* W1 = (const float*)d_in[3];
  const float* b1 = (const float*)d_in[4];
  const float* W2 = (const float*)d_in[5];
  const float* b2 = (const float*)d_in[6];
  const float* E1 = (const float*)d_in[7];
  const float* e1 = (const float*)d_in[8];
  const float* E2 = (const float*)d_in[9];
  const float* e2 = (const float*)d_in[10];
  const float* init_logits = (const float*)d_in[11];
  float* out = (float*)d_out;

  char* wsb = (char*)d_ws;
  float* ltrans = (float*)(wsb + 0);         // 2,097,152 B
  u16* h2b = (u16*)(wsb + 2097152);          //   131,072 B
  u16* h1b = (u16*)(wsb + 2228224);          //   131,072 B
  u16* E2bT = (u16*)(wsb + 2359296);         // 4,194,304 B -> 6,553,600
  u16* W2T = (u16*)(wsb + 6553600);          //   262,144 B -> 6,815,744
  float* lse2 = (float*)(wsb + 6815744);     //    65,536 B -> 6,881,280

  k_prep1<<<1120, 256, 0, stream>>>(E2, E2bT, W2, W2T, emb, W1, b1, E1, e1,
                                    h1b, h2b);
  k_tables<<<640, 256, 0, stream>>>(h1b, W2T, b2, ltrans, h2b, E2bT, e2, lse2);
  k_matfinal<<<16, 1024, 0, stream>>>(seq, lengths, ltrans, h2b, E2bT, e2,
                                      lse2, init_logits, out);
}

// Round 10
// 83.105 us; speedup vs baseline: 3.8133x; 3.8133x over previous
//
#include <hip/hip_runtime.h>
#include <hip/hip_bf16.h>

// Problem constants
#define BB 16
#define TT 512
#define KK 32
#define VV 512
#define DD 64
#define HH 128
#define KV (KK*VV)   // 16384
#define KKK (KK*KK)  // 1024

#define INV_LN2 1.4426950408889634f
#define LN2 0.6931471805599453f

typedef unsigned short u16;
typedef __attribute__((ext_vector_type(8))) short short8;
typedef __attribute__((ext_vector_type(8))) unsigned short ushort8;
typedef __attribute__((ext_vector_type(16))) float f32x16;
typedef __attribute__((ext_vector_type(4))) unsigned int uint4v;

__device__ __forceinline__ float fexp2(float x) { return __builtin_amdgcn_exp2f(x); }
__device__ __forceinline__ float flog2(float x) { return __builtin_amdgcn_logf(x); }

// float -> bf16 bits, round-nearest-even (finite inputs only)
__device__ __forceinline__ u16 f2bf(float f) {
  unsigned u = __builtin_bit_cast(unsigned, f);
  u += 0x7FFFu + ((u >> 16) & 1u);
  return (u16)(u >> 16);
}
__device__ __forceinline__ float bf2f(u16 v) {
  return __builtin_bit_cast(float, ((unsigned)v) << 16);
}

// 128-dim half-dot of two bf16 rows (64 elements each, this lane's half),
// 4 independent accumulators to break the serial FMA chain.
__device__ __forceinline__ float es_dot(const u16* __restrict__ erow,
                                        const u16* __restrict__ hrow) {
  float a0 = 0.f, a1 = 0.f, a2 = 0.f, a3 = 0.f;
#pragma unroll
  for (int r = 0; r < 8; ++r) {
    short8 ev = ((const short8*)erow)[r];
    short8 hv = ((const short8*)hrow)[r];
    a0 += bf2f((u16)ev[0]) * bf2f((u16)hv[0]);
    a1 += bf2f((u16)ev[1]) * bf2f((u16)hv[1]);
    a2 += bf2f((u16)ev[2]) * bf2f((u16)hv[2]);
    a3 += bf2f((u16)ev[3]) * bf2f((u16)hv[3]);
    a0 += bf2f((u16)ev[4]) * bf2f((u16)hv[4]);
    a1 += bf2f((u16)ev[5]) * bf2f((u16)hv[5]);
    a2 += bf2f((u16)ev[6]) * bf2f((u16)hv[6]);
    a3 += bf2f((u16)ev[7]) * bf2f((u16)hv[7]);
  }
  return (a0 + a1) + (a2 + a3);
}

// One step of the 32x32 matrix-chain product: D = A(fr0,fr1) x D.
// D layout: lane(l) col=l&31, rows (r&3)+8*(r>>2)+4*(l>>5).
__device__ __forceinline__ void mul_step(short8 fr0, short8 fr1, int h,
                                         float* D) {
  float e0[8], e1[8];
#pragma unroll
  for (int i2 = 0; i2 < 4; ++i2) {
    float x0 = __shfl_xor(D[i2], 32);
    float y0 = __shfl_xor(D[4 + i2], 32);
    e0[i2] = (h == 0) ? D[i2] : y0;
    e0[4 + i2] = (h == 0) ? x0 : D[4 + i2];
    float x1 = __shfl_xor(D[8 + i2], 32);
    float y1 = __shfl_xor(D[12 + i2], 32);
    e1[i2] = (h == 0) ? D[8 + i2] : y1;
    e1[4 + i2] = (h == 0) ? x1 : D[12 + i2];
  }
  short8 B0, B1;
#pragma unroll
  for (int e = 0; e < 8; ++e) {
    B0[e] = (short)f2bf(e0[e]);
    B1[e] = (short)f2bf(e1[e]);
  }
  f32x16 dn = {};
  dn = __builtin_amdgcn_mfma_f32_32x32x16_bf16(fr0, B0, dn, 0, 0, 0);
  dn = __builtin_amdgcn_mfma_f32_32x32x16_bf16(fr1, B1, dn, 0, 0, 0);
#pragma unroll
  for (int r = 0; r < 16; ++r) D[r] = dn[r];
}

__device__ __forceinline__ void ident_D(int j, int h, float* D) {
#pragma unroll
  for (int r = 0; r < 16; ++r) D[r] = 0.f;
  if (((j >> 2) & 1) == h) D[(j & 3) | ((j >> 3) << 2)] = 1.0f;
}

// ---------------------------------------------------------------------------
// K0: merged prep.
//  blocks [0,1024):    LDS-tiled transpose E2 (128x16384 f32) -> E2bT bf16
//                      [k*512+y][h] AND E2yT bf16 [y*32+k][h]
//  blocks [1024,1088): LDS-tiled transpose W2 (128x1024 f32)  -> W2T  bf16
//  blocks [1088,1120): hidden activations h1b/h2b (bf16), 16 tokens/block
__global__ __launch_bounds__(256) void k_prep1(
    const float* __restrict__ E2, u16* __restrict__ E2bT,
    u16* __restrict__ E2yT, const float* __restrict__ W2,
    u16* __restrict__ W2T, const float* __restrict__ emb,
    const float* __restrict__ W1, const float* __restrict__ b1,
    const float* __restrict__ E1, const float* __restrict__ e1,
    u16* __restrict__ h1b, u16* __restrict__ h2b) {
  __shared__ float tl[32][65];
  __shared__ float embs[16][64];
  int tid = threadIdx.x;
  int bid = blockIdx.x;

  if (bid < 1088) {
    // ---- transpose tile: 32 h x 64 col ----
    const float* src;
    u16* dst;
    size_t srcld;
    int c0, h0;
    int isE2 = (bid < 1024);
    if (isE2) {
      c0 = (bid & 255) * 64;
      h0 = (bid >> 8) * 32;
      src = E2;
      dst = E2bT;
      srcld = KV;
    } else {
      int b2i = bid - 1024;
      c0 = (b2i & 15) * 64;
      h0 = (b2i >> 4) * 32;
      src = W2;
      dst = W2T;
      srcld = KKK;
    }
    int r = tid >> 6, c = tid & 63;
#pragma unroll
    for (int rr = 0; rr < 8; ++rr)
      tl[r * 8 + rr][c] = src[(size_t)(h0 + r * 8 + rr) * srcld + c0 + c];
    __syncthreads();
    int cw = tid >> 3, hb = tid & 7;
#pragma unroll
    for (int pass = 0; pass < 2; ++pass) {
      int cc = pass * 32 + cw;
      unsigned lo = (unsigned)f2bf(tl[hb * 4 + 0][cc]) |
                    ((unsigned)f2bf(tl[hb * 4 + 1][cc]) << 16);
      unsigned hi = (unsigned)f2bf(tl[hb * 4 + 2][cc]) |
                    ((unsigned)f2bf(tl[hb * 4 + 3][cc]) << 16);
      uint2 v;
      v.x = lo;
      v.y = hi;
      int col = c0 + cc;
      *(uint2*)(dst + (size_t)col * HH + h0 + hb * 4) = v;
      if (isE2) {
        int k = col >> 9, y = col & 511;
        *(uint2*)(E2yT + ((size_t)y * KK + k) * HH + h0 + hb * 4) = v;
      }
    }
    return;
  }

  // ---- hidden: 16 tokens ----
  int u0 = (bid - 1088) * 16;
#pragma unroll
  for (int it = 0; it < 4; ++it) {
    int idx = it * 256 + tid;
    embs[idx >> 6][idx & 63] = emb[u0 * DD + idx];
  }
  __syncthreads();
  int h = tid & 127, tl2 = tid >> 7;
  float b1v = b1[h], e1v = e1[h];
#pragma unroll
  for (int it = 0; it < 8; ++it) {
    int tok = it * 2 + tl2;
    float a1 = b1v, a2 = e1v;
#pragma unroll 8
    for (int d = 0; d < DD; ++d) {
      float xv = embs[tok][d];
      a1 += xv * W1[d * HH + h];
      a2 += xv * E1[d * HH + h];
    }
    h1b[(u0 + tok) * HH + h] = f2bf(fmaxf(a1, 0.f));
    h2b[(u0 + tok) * HH + h] = f2bf(fmaxf(a2, 0.f));
  }
}

// ---------------------------------------------------------------------------
// K1: merged tables kernel.
//  blocks [0,512):   emission GEMM via MFMA + fused LSE over V (no-max).
//  blocks [512,640): transition tables via MFMA + fused log2-softmax.
__global__ __launch_bounds__(256) void k_tables(
    const u16* __restrict__ h1b, const u16* __restrict__ W2T,
    const float* __restrict__ b2, float* __restrict__ ltrans,
    const u16* __restrict__ h2b, const u16* __restrict__ E2bT,
    const float* __restrict__ e2, float* __restrict__ lse2_tab) {
  __shared__ float ls[4 * 32];
  int bid = blockIdx.x;
  int tid = threadIdx.x;
  int w = tid >> 6, l = tid & 63;
  int h = l >> 5, j = l & 31;

  if (bid < 512) {
    // ---- emission LSE ----
    int k = bid & 31;
    int u0 = (bid >> 5) * 32;

    short8 A[8];
#pragma unroll
    for (int kh = 0; kh < 8; ++kh)
      A[kh] = *(const short8*)(h2b + (u0 + j) * HH + kh * 16 + h * 8);

    float s[16];
#pragma unroll
    for (int r = 0; r < 16; ++r) s[r] = 0.f;

#pragma unroll
    for (int c = 0; c < 4; ++c) {
      int ct = w * 4 + c;
      int col = k * 512 + ct * 32 + j;
      const u16* bp = E2bT + (size_t)col * HH + h * 8;
      f32x16 acc = {};
#pragma unroll
      for (int kh = 0; kh < 8; ++kh) {
        short8 Bf = *(const short8*)(bp + kh * 16);
        acc = __builtin_amdgcn_mfma_f32_32x32x16_bf16(A[kh], Bf, acc, 0, 0, 0);
      }
      float e2v = e2[col] * INV_LN2;
#pragma unroll
      for (int r = 0; r < 16; ++r) s[r] += fexp2(acc[r] * INV_LN2 + e2v);
    }
#pragma unroll
    for (int r = 0; r < 16; ++r) {
#pragma unroll
      for (int d = 1; d < 32; d <<= 1) s[r] += __shfl_xor(s[r], d);
    }
    if (j == 0) {
#pragma unroll
      for (int r = 0; r < 16; ++r) {
        int row = (r & 3) + 8 * (r >> 2) + 4 * h;
        ls[w * 32 + row] = s[r];
      }
    }
    __syncthreads();
    if (tid < 32) {
      float total = ls[tid] + ls[32 + tid] + ls[64 + tid] + ls[96 + tid];
      lse2_tab[(u0 + tid) * KK + k] = flog2(total);
    }
    return;
  }

  // ---- transition tables ----
  int t2 = bid - 512;
  int i = t2 & 31;
  int tt = (t2 >> 5) * 4 + w;
  int u0 = tt * 32;

  f32x16 acc = {};
#pragma unroll
  for (int kh = 0; kh < 8; ++kh) {
    short8 A = *(const short8*)(h1b + (u0 + j) * HH + kh * 16 + h * 8);
    short8 Bf = *(const short8*)(W2T + (i * 32 + j) * HH + kh * 16 + h * 8);
    acc = __builtin_amdgcn_mfma_f32_32x32x16_bf16(A, Bf, acc, 0, 0, 0);
  }
  float b2v = b2[i * 32 + j] * INV_LN2;
  float lgv[16], se[16];
#pragma unroll
  for (int r = 0; r < 16; ++r) {
    lgv[r] = acc[r] * INV_LN2 + b2v;
    se[r] = fexp2(lgv[r]);
  }
#pragma unroll
  for (int r = 0; r < 16; ++r) {
#pragma unroll
    for (int d = 1; d < 32; d <<= 1) se[r] += __shfl_xor(se[r], d);
  }
#pragma unroll
  for (int r = 0; r < 16; ++r) {
    int row = (r & 3) + 8 * (r >> 2) + 4 * h;
    ltrans[(u0 + row) * KKK + j * KK + i] = lgv[r] - flog2(se[r]);
  }
}

// ---------------------------------------------------------------------------
// K2: fused es + step-matrix build + chunk-of-8 product (R6 geometry).
// grid 256 x 256 (4 waves/block); wave handles chunk c = bid*4+w of 1024.
// es gather uses E2yT [y*32+k][h]: 64 lanes read one contiguous 8KB block.
// No fences, no atomics.
__global__ __launch_bounds__(256) void k_matprod(
    const int* __restrict__ seq, const int* __restrict__ lengths,
    const float* __restrict__ ltrans, const u16* __restrict__ h2b,
    const u16* __restrict__ E2yT, const float* __restrict__ e2,
    const float* __restrict__ lse2, u16* __restrict__ C1,
    float* __restrict__ s1) {
  __shared__ float tmp[4][32 * 33];
  int w = threadIdx.x >> 6, l = threadIdx.x & 63;
  int c = blockIdx.x * 4 + w;
  int b = c >> 6, t0 = (c & 63) * 8;
  int j = l & 31, h = l >> 5;
  int len = lengths[b];
  len = (len < 1) ? 1 : ((len > TT) ? TT : len);
  const int* sb = seq + b * TT;
  int tlo = (t0 < 1) ? 1 : t0;
  int thi = (t0 + 8 < len) ? (t0 + 8) : len;

  u16* op = C1 + (size_t)c * 1024 + j * 32 + h * 16;
  if (tlo >= thi) {  // fully identity chunk (wave-uniform)
    ushort8 w0v, w1v;
#pragma unroll
    for (int e = 0; e < 8; ++e) {
      w0v[e] = ((h * 16 + e) == j) ? (u16)0x3F80 : (u16)0;
      w1v[e] = ((h * 16 + 8 + e) == j) ? (u16)0x3F80 : (u16)0;
    }
    *(ushort8*)op = w0v;
    *(ushort8*)(op + 8) = w1v;
    if (l == 0) s1[c] = 0.f;
    return;
  }

  // ---- Phase A: build 8 fragment pairs ----
  short8 fr0s[8], fr1s[8];
  float sacc = 0.f;
#pragma unroll
  for (int s = 0; s < 8; ++s) {
    int t = t0 + s;
    if (t >= 1 && t < len) {  // wave-uniform
      int u = sb[t - 1], y = sb[t];
      float dot = es_dot(E2yT + ((size_t)y * KK + j) * HH + h * 64,
                         h2b + u * HH + h * 64);
      dot += __shfl_xor(dot, 32);
      float esj = (dot + e2[j * VV + y]) * INV_LN2 - lse2[u * KK + j];
      float m = esj;  // scale = max_j esj (ltrans rows are <= 0)
#pragma unroll
      for (int d = 1; d < 32; d <<= 1) m = fmaxf(m, __shfl_xor(m, d));
      sacc += m;
      const float4* p4 = (const float4*)(ltrans + u * KKK + j * KK + h * 16);
      float4 q0 = p4[0], q1 = p4[1], q2 = p4[2], q3 = p4[3];
      float lgv[16] = {q0.x, q0.y, q0.z, q0.w, q1.x, q1.y, q1.z, q1.w,
                       q2.x, q2.y, q2.z, q2.w, q3.x, q3.y, q3.z, q3.w};
      float off = esj - m;
#pragma unroll
      for (int e = 0; e < 16; ++e) lgv[e] += off;
      unsigned pk[8];
#pragma unroll
      for (int p = 0; p < 8; ++p)
        pk[p] = (unsigned)f2bf(fexp2(lgv[2 * p])) |
                ((unsigned)f2bf(fexp2(lgv[2 * p + 1])) << 16);
      unsigned rcv[4];
#pragma unroll
      for (int p = 0; p < 4; ++p)
        rcv[p] = (unsigned)__shfl_xor((int)(h == 0 ? pk[4 + p] : pk[p]), 32);
      unsigned f0[4], f1[4];
#pragma unroll
      for (int p = 0; p < 4; ++p) {
        f0[p] = h == 0 ? pk[p] : rcv[p];
        f1[p] = h == 0 ? rcv[p] : pk[4 + p];
      }
      fr0s[s] = __builtin_bit_cast(short8, (uint4v){f0[0], f0[1], f0[2], f0[3]});
      fr1s[s] = __builtin_bit_cast(short8, (uint4v){f1[0], f1[1], f1[2], f1[3]});
    } else {
      // identity A-fragment: fr0 covers k h*8+e, fr1 k 16+h*8+e
      ushort8 i0, i1;
#pragma unroll
      for (int e = 0; e < 8; ++e) {
        i0[e] = ((h * 8 + e) == j) ? (u16)0x3F80 : (u16)0;
        i1[e] = ((16 + h * 8 + e) == j) ? (u16)0x3F80 : (u16)0;
      }
      fr0s[s] = __builtin_bit_cast(short8, i0);
      fr1s[s] = __builtin_bit_cast(short8, i1);
    }
  }

  // ---- Phase B: chained product ----
  float D[16];
  ident_D(j, h, D);
#pragma unroll
  for (int s = 0; s < 8; ++s) mul_step(fr0s[s], fr1s[s], h, D);

  // normalize D and emit row-major bf16 + scale
  float mx = D[0];
#pragma unroll
  for (int r = 1; r < 16; ++r) mx = fmaxf(mx, D[r]);
#pragma unroll
  for (int d = 1; d < 64; d <<= 1) mx = fmaxf(mx, __shfl_xor(mx, d));
  float inv = 1.0f / mx;
#pragma unroll
  for (int r = 0; r < 16; ++r) {
    int row = (r & 3) + 8 * (r >> 2) + 4 * h;
    tmp[w][row * 33 + j] = D[r] * inv;
  }
  ushort8 w0v, w1v;
#pragma unroll
  for (int e = 0; e < 8; ++e) {
    w0v[e] = f2bf(tmp[w][j * 33 + h * 16 + e]);
    w1v[e] = f2bf(tmp[w][j * 33 + h * 16 + 8 + e]);
  }
  *(ushort8*)op = w0v;
  *(ushort8*)(op + 8) = w1v;
  if (l == 0) s1[c] = flog2(mx) + sacc;
}

// ---------------------------------------------------------------------------
// K3: final reduce. 16 blocks x 512 (8 waves). Wave w: product of 8 C1 chunks
// -> LDS. Wave 0: product of the 8 LDS mats + alpha0/es(t=0) + NLL.
__global__ __launch_bounds__(512) void k_final2(
    const u16* __restrict__ C1, const float* __restrict__ s1,
    const int* __restrict__ seq, const u16* __restrict__ h2b,
    const u16* __restrict__ E2yT, const float* __restrict__ e2,
    const float* __restrict__ lse2, const float* __restrict__ init_logits,
    float* __restrict__ out) {
  __shared__ u16 mats[8][1024];
  __shared__ float scs[8];
  int b = blockIdx.x;
  int w = threadIdx.x >> 6, l = threadIdx.x & 63;
  int j = l & 31, h = l >> 5;

  float D[16];
  ident_D(j, h, D);
  const u16* base = C1 + ((size_t)b * 64 + w * 8) * 1024;
#pragma unroll
  for (int s = 0; s < 8; ++s) {
    short8 fr0 = *(const short8*)(base + s * 1024 + j * 32 + h * 8);
    short8 fr1 = *(const short8*)(base + s * 1024 + j * 32 + h * 8 + 16);
    mul_step(fr0, fr1, h, D);
  }
  float mx = D[0];
#pragma unroll
  for (int r = 1; r < 16; ++r) mx = fmaxf(mx, D[r]);
#pragma unroll
  for (int d = 1; d < 64; d <<= 1) mx = fmaxf(mx, __shfl_xor(mx, d));
  float inv = 1.0f / mx;
#pragma unroll
  for (int r = 0; r < 16; ++r) {
    int row = (r & 3) + 8 * (r >> 2) + 4 * h;
    mats[w][row * 32 + j] = f2bf(D[r] * inv);
  }
  float si = (l < 8) ? s1[b * 64 + w * 8 + l] : 0.f;
#pragma unroll
  for (int d = 1; d < 64; d <<= 1) si += __shfl_xor(si, d);
  if (l == 0) scs[w] = flog2(mx) + si;
  __syncthreads();

  if (w == 0) {
    float D2[16];
    ident_D(j, h, D2);
#pragma unroll
    for (int s = 0; s < 8; ++s) {
      short8 fr0 = *(const short8*)(&mats[s][j * 32 + h * 8]);
      short8 fr1 = *(const short8*)(&mats[s][j * 32 + h * 8 + 16]);
      mul_step(fr0, fr1, h, D2);
    }
    // es(b, 0, j): input token at t=0 is the start token 0
    int y0 = seq[b * TT];
    float dot = es_dot(E2yT + ((size_t)y0 * KK + j) * HH + h * 64,
                       h2b + h * 64);
    dot += __shfl_xor(dot, 32);
    float esj = (dot + e2[j * VV + y0]) * INV_LN2 - lse2[j];
    // alpha0 (log2 domain)
    float il = init_logits[j] * INV_LN2;
    float m0 = il;
#pragma unroll
    for (int d = 1; d < 32; d <<= 1) m0 = fmaxf(m0, __shfl_xor(m0, d));
    float s0 = fexp2(il - m0);
#pragma unroll
    for (int d = 1; d < 32; d <<= 1) s0 += __shfl_xor(s0, d);
    float lse0 = m0 + flog2(s0);
    float z = il - lse0 + esj;
    float am = z;
#pragma unroll
    for (int d = 1; d < 32; d <<= 1) am = fmaxf(am, __shfl_xor(am, d));
    float a0 = fexp2(z - am);
    float colsum = 0.f;
#pragma unroll
    for (int r = 0; r < 16; ++r) colsum += D2[r];
    float p = a0 * colsum;
#pragma unroll
    for (int d = 1; d < 64; d <<= 1) p += __shfl_xor(p, d);
    float sct = (l < 8) ? scs[l] : 0.f;
#pragma unroll
    for (int d = 1; d < 64; d <<= 1) sct += __shfl_xor(sct, d);
    if (l == 0) out[b] = -LN2 * (flog2(p) + am + sct);
  }
}

// ---------------------------------------------------------------------------
extern "C" void kernel_launch(void* const* d_in, const int* in_sizes, int n_in,
                              void* d_out, int out_size, void* d_ws,
                              size_t ws_size, hipStream_t stream) {
  const int* seq = (const int*)d_in[0];
  const int* lengths = (const int*)d_in[1];
  const float* emb = (const float*)d_in[2];
  const float* W1 = (const float*)d_in[3];
  const float* b1 = (const float*)d_in[4];
  const float* W2 = (const float*)d_in[5];
  const float* b2 = (const float*)d_in[6];
  const float* E1 = (const float*)d_in[7];
  const float* e1 = (const float*)d_in[8];
  const float* E2 = (const float*)d_in[9];
  const float* e2 = (const float*)d_in[10];
  const float* init_logits = (const float*)d_in[11];
  float* out = (float*)d_out;

  char* wsb = (char*)d_ws;
  float* ltrans = (float*)(wsb + 0);         // 2,097,152 B
  u16* h2b = (u16*)(wsb + 2097152);          //   131,072 B
  u16* h1b = (u16*)(wsb + 2228224);          //   131,072 B
  u16* E2bT = (u16*)(wsb + 2359296);         // 4,194,304 B -> 6,553,600
  u16* W2T = (u16*)(wsb + 6553600);          //   262,144 B -> 6,815,744
  float* lse2 = (float*)(wsb + 6815744);     //    65,536 B -> 6,881,280
  u16* C1 = (u16*)(wsb + 6881280);           // 2,097,152 B -> 8,978,432
  float* s1 = (float*)(wsb + 8978432);       //     4,096 B -> 8,982,528
  u16* E2yT = (u16*)(wsb + 8982528);         // 4,194,304 B -> 13,176,832

  k_prep1<<<1120, 256, 0, stream>>>(E2, E2bT, E2yT, W2, W2T, emb, W1, b1, E1,
                                    e1, h1b, h2b);
  k_tables<<<640, 256, 0, stream>>>(h1b, W2T, b2, ltrans, h2b, E2bT, e2, lse2);
  k_matprod<<<256, 256, 0, stream>>>(seq, lengths, ltrans, h2b, E2yT, e2,
                                     lse2, C1, s1);
  k_final2<<<16, 512, 0, stream>>>(C1, s1, seq, h2b, E2yT, e2, lse2,
                                   init_logits, out);
}

// Round 11
// 81.596 us; speedup vs baseline: 3.8839x; 1.0185x over previous
//
#include <hip/hip_runtime.h>
#include <hip/hip_bf16.h>

// Problem constants
#define BB 16
#define TT 512
#define KK 32
#define VV 512
#define DD 64
#define HH 128
#define KV (KK*VV)   // 16384
#define KKK (KK*KK)  // 1024

#define INV_LN2 1.4426950408889634f
#define LN2 0.6931471805599453f

typedef unsigned short u16;
typedef __attribute__((ext_vector_type(8))) short short8;
typedef __attribute__((ext_vector_type(8))) unsigned short ushort8;
typedef __attribute__((ext_vector_type(16))) float f32x16;
typedef __attribute__((ext_vector_type(4))) unsigned int uint4v;

__device__ __forceinline__ float fexp2(float x) { return __builtin_amdgcn_exp2f(x); }
__device__ __forceinline__ float flog2(float x) { return __builtin_amdgcn_logf(x); }

// float -> bf16 bits, round-nearest-even (finite inputs only)
__device__ __forceinline__ u16 f2bf(float f) {
  unsigned u = __builtin_bit_cast(unsigned, f);
  u += 0x7FFFu + ((u >> 16) & 1u);
  return (u16)(u >> 16);
}
__device__ __forceinline__ float bf2f(u16 v) {
  return __builtin_bit_cast(float, ((unsigned)v) << 16);
}

// 128-dim half-dot of two bf16 rows (64 elements each, this lane's half),
// 4 independent accumulators to break the serial FMA chain.
__device__ __forceinline__ float es_dot(const u16* __restrict__ erow,
                                        const u16* __restrict__ hrow) {
  float a0 = 0.f, a1 = 0.f, a2 = 0.f, a3 = 0.f;
#pragma unroll
  for (int r = 0; r < 8; ++r) {
    short8 ev = ((const short8*)erow)[r];
    short8 hv = ((const short8*)hrow)[r];
    a0 += bf2f((u16)ev[0]) * bf2f((u16)hv[0]);
    a1 += bf2f((u16)ev[1]) * bf2f((u16)hv[1]);
    a2 += bf2f((u16)ev[2]) * bf2f((u16)hv[2]);
    a3 += bf2f((u16)ev[3]) * bf2f((u16)hv[3]);
    a0 += bf2f((u16)ev[4]) * bf2f((u16)hv[4]);
    a1 += bf2f((u16)ev[5]) * bf2f((u16)hv[5]);
    a2 += bf2f((u16)ev[6]) * bf2f((u16)hv[6]);
    a3 += bf2f((u16)ev[7]) * bf2f((u16)hv[7]);
  }
  return (a0 + a1) + (a2 + a3);
}

// One step of the 32x32 matrix-chain product: D = A(fr0,fr1) x D.
// D layout: lane(l) col=l&31, rows (r&3)+8*(r>>2)+4*(l>>5).
__device__ __forceinline__ void mul_step(short8 fr0, short8 fr1, int h,
                                         float* D) {
  float e0[8], e1[8];
#pragma unroll
  for (int i2 = 0; i2 < 4; ++i2) {
    float x0 = __shfl_xor(D[i2], 32);
    float y0 = __shfl_xor(D[4 + i2], 32);
    e0[i2] = (h == 0) ? D[i2] : y0;
    e0[4 + i2] = (h == 0) ? x0 : D[4 + i2];
    float x1 = __shfl_xor(D[8 + i2], 32);
    float y1 = __shfl_xor(D[12 + i2], 32);
    e1[i2] = (h == 0) ? D[8 + i2] : y1;
    e1[4 + i2] = (h == 0) ? x1 : D[12 + i2];
  }
  short8 B0, B1;
#pragma unroll
  for (int e = 0; e < 8; ++e) {
    B0[e] = (short)f2bf(e0[e]);
    B1[e] = (short)f2bf(e1[e]);
  }
  f32x16 dn = {};
  dn = __builtin_amdgcn_mfma_f32_32x32x16_bf16(fr0, B0, dn, 0, 0, 0);
  dn = __builtin_amdgcn_mfma_f32_32x32x16_bf16(fr1, B1, dn, 0, 0, 0);
#pragma unroll
  for (int r = 0; r < 16; ++r) D[r] = dn[r];
}

__device__ __forceinline__ void ident_D(int j, int h, float* D) {
#pragma unroll
  for (int r = 0; r < 16; ++r) D[r] = 0.f;
  if (((j >> 2) & 1) == h) D[(j & 3) | ((j >> 3) << 2)] = 1.0f;
}

// ---------------------------------------------------------------------------
// K0: merged prep.
//  blocks [0,1024):    LDS-tiled transpose E2 (128x16384 f32) -> E2bT bf16
//                      [k*512+y][h] AND E2yT bf16 [y*32+k][h]
//  blocks [1024,1088): LDS-tiled transpose W2 (128x1024 f32)  -> W2T  bf16
//  blocks [1088,1120): hidden activations h1b/h2b (bf16), 16 tokens/block
__global__ __launch_bounds__(256) void k_prep1(
    const float* __restrict__ E2, u16* __restrict__ E2bT,
    u16* __restrict__ E2yT, const float* __restrict__ W2,
    u16* __restrict__ W2T, const float* __restrict__ emb,
    const float* __restrict__ W1, const float* __restrict__ b1,
    const float* __restrict__ E1, const float* __restrict__ e1,
    u16* __restrict__ h1b, u16* __restrict__ h2b) {
  __shared__ float tl[32][65];
  __shared__ float embs[16][64];
  int tid = threadIdx.x;
  int bid = blockIdx.x;

  if (bid < 1088) {
    // ---- transpose tile: 32 h x 64 col ----
    const float* src;
    u16* dst;
    size_t srcld;
    int c0, h0;
    int isE2 = (bid < 1024);
    if (isE2) {
      c0 = (bid & 255) * 64;
      h0 = (bid >> 8) * 32;
      src = E2;
      dst = E2bT;
      srcld = KV;
    } else {
      int b2i = bid - 1024;
      c0 = (b2i & 15) * 64;
      h0 = (b2i >> 4) * 32;
      src = W2;
      dst = W2T;
      srcld = KKK;
    }
    int r = tid >> 6, c = tid & 63;
#pragma unroll
    for (int rr = 0; rr < 8; ++rr)
      tl[r * 8 + rr][c] = src[(size_t)(h0 + r * 8 + rr) * srcld + c0 + c];
    __syncthreads();
    int cw = tid >> 3, hb = tid & 7;
#pragma unroll
    for (int pass = 0; pass < 2; ++pass) {
      int cc = pass * 32 + cw;
      unsigned lo = (unsigned)f2bf(tl[hb * 4 + 0][cc]) |
                    ((unsigned)f2bf(tl[hb * 4 + 1][cc]) << 16);
      unsigned hi = (unsigned)f2bf(tl[hb * 4 + 2][cc]) |
                    ((unsigned)f2bf(tl[hb * 4 + 3][cc]) << 16);
      uint2 v;
      v.x = lo;
      v.y = hi;
      int col = c0 + cc;
      *(uint2*)(dst + (size_t)col * HH + h0 + hb * 4) = v;
      if (isE2) {
        int k = col >> 9, y = col & 511;
        *(uint2*)(E2yT + ((size_t)y * KK + k) * HH + h0 + hb * 4) = v;
      }
    }
    return;
  }

  // ---- hidden: 16 tokens ----
  int u0 = (bid - 1088) * 16;
#pragma unroll
  for (int it = 0; it < 4; ++it) {
    int idx = it * 256 + tid;
    embs[idx >> 6][idx & 63] = emb[u0 * DD + idx];
  }
  __syncthreads();
  int h = tid & 127, tl2 = tid >> 7;
  float b1v = b1[h], e1v = e1[h];
#pragma unroll
  for (int it = 0; it < 8; ++it) {
    int tok = it * 2 + tl2;
    float a1 = b1v, a2 = e1v;
#pragma unroll 8
    for (int d = 0; d < DD; ++d) {
      float xv = embs[tok][d];
      a1 += xv * W1[d * HH + h];
      a2 += xv * E1[d * HH + h];
    }
    h1b[(u0 + tok) * HH + h] = f2bf(fmaxf(a1, 0.f));
    h2b[(u0 + tok) * HH + h] = f2bf(fmaxf(a2, 0.f));
  }
}

// ---------------------------------------------------------------------------
// K1: merged tables kernel.
//  blocks [0,512):   emission GEMM via MFMA + fused LSE over V (no-max).
//  blocks [512,640): transition tables via MFMA + fused log2-softmax.
__global__ __launch_bounds__(256) void k_tables(
    const u16* __restrict__ h1b, const u16* __restrict__ W2T,
    const float* __restrict__ b2, float* __restrict__ ltrans,
    const u16* __restrict__ h2b, const u16* __restrict__ E2bT,
    const float* __restrict__ e2, float* __restrict__ lse2_tab) {
  __shared__ float ls[4 * 32];
  int bid = blockIdx.x;
  int tid = threadIdx.x;
  int w = tid >> 6, l = tid & 63;
  int h = l >> 5, j = l & 31;

  if (bid < 512) {
    // ---- emission LSE ----
    int k = bid & 31;
    int u0 = (bid >> 5) * 32;

    short8 A[8];
#pragma unroll
    for (int kh = 0; kh < 8; ++kh)
      A[kh] = *(const short8*)(h2b + (u0 + j) * HH + kh * 16 + h * 8);

    float s[16];
#pragma unroll
    for (int r = 0; r < 16; ++r) s[r] = 0.f;

#pragma unroll
    for (int c = 0; c < 4; ++c) {
      int ct = w * 4 + c;
      int col = k * 512 + ct * 32 + j;
      const u16* bp = E2bT + (size_t)col * HH + h * 8;
      f32x16 acc = {};
#pragma unroll
      for (int kh = 0; kh < 8; ++kh) {
        short8 Bf = *(const short8*)(bp + kh * 16);
        acc = __builtin_amdgcn_mfma_f32_32x32x16_bf16(A[kh], Bf, acc, 0, 0, 0);
      }
      float e2v = e2[col] * INV_LN2;
#pragma unroll
      for (int r = 0; r < 16; ++r) s[r] += fexp2(acc[r] * INV_LN2 + e2v);
    }
#pragma unroll
    for (int r = 0; r < 16; ++r) {
#pragma unroll
      for (int d = 1; d < 32; d <<= 1) s[r] += __shfl_xor(s[r], d);
    }
    if (j == 0) {
#pragma unroll
      for (int r = 0; r < 16; ++r) {
        int row = (r & 3) + 8 * (r >> 2) + 4 * h;
        ls[w * 32 + row] = s[r];
      }
    }
    __syncthreads();
    if (tid < 32) {
      float total = ls[tid] + ls[32 + tid] + ls[64 + tid] + ls[96 + tid];
      lse2_tab[(u0 + tid) * KK + k] = flog2(total);
    }
    return;
  }

  // ---- transition tables ----
  int t2 = bid - 512;
  int i = t2 & 31;
  int tt = (t2 >> 5) * 4 + w;
  int u0 = tt * 32;

  f32x16 acc = {};
#pragma unroll
  for (int kh = 0; kh < 8; ++kh) {
    short8 A = *(const short8*)(h1b + (u0 + j) * HH + kh * 16 + h * 8);
    short8 Bf = *(const short8*)(W2T + (i * 32 + j) * HH + kh * 16 + h * 8);
    acc = __builtin_amdgcn_mfma_f32_32x32x16_bf16(A, Bf, acc, 0, 0, 0);
  }
  float b2v = b2[i * 32 + j] * INV_LN2;
  float lgv[16], se[16];
#pragma unroll
  for (int r = 0; r < 16; ++r) {
    lgv[r] = acc[r] * INV_LN2 + b2v;
    se[r] = fexp2(lgv[r]);
  }
#pragma unroll
  for (int r = 0; r < 16; ++r) {
#pragma unroll
    for (int d = 1; d < 32; d <<= 1) se[r] += __shfl_xor(se[r], d);
  }
#pragma unroll
  for (int r = 0; r < 16; ++r) {
    int row = (r & 3) + 8 * (r >> 2) + 4 * h;
    ltrans[(u0 + row) * KKK + j * KK + i] = lgv[r] - flog2(se[r]);
  }
}

// ---------------------------------------------------------------------------
// K2: fused es + step-matrix build + chunk product, 2 waves/SIMD geometry.
// grid 256 x 512 (8 waves). Wave pair (2p, 2p+1) shares C1 chunk
// c = bid*4 + p (8 steps): lo wave (even) does steps [t0c, t0c+4),
// hi wave (odd) does [t0c+4, t0c+8). Hi normalizes its product into LDS;
// after one barrier, lo combines (1 mul_step), normalizes, writes C1/s1.
// No fences, no atomics; k_final2 consumes the same 1024-chunk C1.
#define MSTRIDE 40
__global__ __launch_bounds__(512) void k_matprod(
    const int* __restrict__ seq, const int* __restrict__ lengths,
    const float* __restrict__ ltrans, const u16* __restrict__ h2b,
    const u16* __restrict__ E2yT, const float* __restrict__ e2,
    const float* __restrict__ lse2, u16* __restrict__ C1,
    float* __restrict__ s1) {
  __shared__ u16 mats[4][32 * MSTRIDE];
  __shared__ float scs[8];
  __shared__ float tmp[4][32 * 33];
  int w = threadIdx.x >> 6, l = threadIdx.x & 63;
  int pair = w >> 1, hi = w & 1;
  int c = blockIdx.x * 4 + pair;  // C1 chunk 0..1023
  int b = c >> 6, t0c = (c & 63) * 8;
  int t0 = t0c + hi * 4;  // this wave's 4 steps
  int j = l & 31, h = l >> 5;
  int len = lengths[b];
  len = (len < 1) ? 1 : ((len > TT) ? TT : len);
  const int* sb = seq + b * TT;
  int tlo_c = (t0c < 1) ? 1 : t0c;
  int thi_c = (t0c + 8 < len) ? (t0c + 8) : len;
  bool fullid = (tlo_c >= thi_c);  // whole 8-step chunk identity (wave-unif)

  float D[16];
  ident_D(j, h, D);
  float sacc = 0.f;

  if (!fullid) {
    // ---- Phase A: build this wave's 4 fragment pairs ----
    short8 fr0s[4], fr1s[4];
#pragma unroll
    for (int s = 0; s < 4; ++s) {
      int t = t0 + s;
      if (t >= 1 && t < len) {  // wave-uniform
        int u = sb[t - 1], y = sb[t];
        float dot = es_dot(E2yT + ((size_t)y * KK + j) * HH + h * 64,
                           h2b + u * HH + h * 64);
        dot += __shfl_xor(dot, 32);
        float esj = (dot + e2[j * VV + y]) * INV_LN2 - lse2[u * KK + j];
        float m = esj;  // scale = max_j esj (ltrans rows are <= 0)
#pragma unroll
        for (int d = 1; d < 32; d <<= 1) m = fmaxf(m, __shfl_xor(m, d));
        sacc += m;
        const float4* p4 = (const float4*)(ltrans + u * KKK + j * KK + h * 16);
        float4 q0 = p4[0], q1 = p4[1], q2 = p4[2], q3 = p4[3];
        float lgv[16] = {q0.x, q0.y, q0.z, q0.w, q1.x, q1.y, q1.z, q1.w,
                         q2.x, q2.y, q2.z, q2.w, q3.x, q3.y, q3.z, q3.w};
        float off = esj - m;
#pragma unroll
        for (int e = 0; e < 16; ++e) lgv[e] += off;
        unsigned pk[8];
#pragma unroll
        for (int p = 0; p < 8; ++p)
          pk[p] = (unsigned)f2bf(fexp2(lgv[2 * p])) |
                  ((unsigned)f2bf(fexp2(lgv[2 * p + 1])) << 16);
        unsigned rcv[4];
#pragma unroll
        for (int p = 0; p < 4; ++p)
          rcv[p] = (unsigned)__shfl_xor((int)(h == 0 ? pk[4 + p] : pk[p]), 32);
        unsigned f0[4], f1[4];
#pragma unroll
        for (int p = 0; p < 4; ++p) {
          f0[p] = h == 0 ? pk[p] : rcv[p];
          f1[p] = h == 0 ? rcv[p] : pk[4 + p];
        }
        fr0s[s] =
            __builtin_bit_cast(short8, (uint4v){f0[0], f0[1], f0[2], f0[3]});
        fr1s[s] =
            __builtin_bit_cast(short8, (uint4v){f1[0], f1[1], f1[2], f1[3]});
      } else {
        // identity A-fragment: fr0 covers k h*8+e, fr1 k 16+h*8+e
        ushort8 i0, i1;
#pragma unroll
        for (int e = 0; e < 8; ++e) {
          i0[e] = ((h * 8 + e) == j) ? (u16)0x3F80 : (u16)0;
          i1[e] = ((16 + h * 8 + e) == j) ? (u16)0x3F80 : (u16)0;
        }
        fr0s[s] = __builtin_bit_cast(short8, i0);
        fr1s[s] = __builtin_bit_cast(short8, i1);
      }
    }

    // ---- Phase B: chained product of 4 ----
#pragma unroll
    for (int s = 0; s < 4; ++s) mul_step(fr0s[s], fr1s[s], h, D);

    if (hi) {
      // hi wave: normalize and publish its product + scale to LDS
      float mx = D[0];
#pragma unroll
      for (int r = 1; r < 16; ++r) mx = fmaxf(mx, D[r]);
#pragma unroll
      for (int d = 1; d < 64; d <<= 1) mx = fmaxf(mx, __shfl_xor(mx, d));
      float inv = 1.0f / mx;
#pragma unroll
      for (int r = 0; r < 16; ++r) {
        int row = (r & 3) + 8 * (r >> 2) + 4 * h;
        mats[pair][row * MSTRIDE + j] = f2bf(D[r] * inv);
      }
      if (l == 0) scs[w] = flog2(mx) + sacc;
    }
  }
  __syncthreads();
  if (hi) return;

  u16* op = C1 + (size_t)c * 1024 + j * 32 + h * 16;
  if (fullid) {  // identity chunk
    ushort8 w0v, w1v;
#pragma unroll
    for (int e = 0; e < 8; ++e) {
      w0v[e] = ((h * 16 + e) == j) ? (u16)0x3F80 : (u16)0;
      w1v[e] = ((h * 16 + 8 + e) == j) ? (u16)0x3F80 : (u16)0;
    }
    *(ushort8*)op = w0v;
    *(ushort8*)(op + 8) = w1v;
    if (l == 0) s1[c] = 0.f;
    return;
  }

  // combine: chunk product = M_hi x M_lo
  {
    short8 fr0 = *(const short8*)(&mats[pair][j * MSTRIDE + h * 8]);
    short8 fr1 = *(const short8*)(&mats[pair][j * MSTRIDE + h * 8 + 16]);
    mul_step(fr0, fr1, h, D);
  }

  // normalize D and emit row-major bf16 + scale
  float mx = D[0];
#pragma unroll
  for (int r = 1; r < 16; ++r) mx = fmaxf(mx, D[r]);
#pragma unroll
  for (int d = 1; d < 64; d <<= 1) mx = fmaxf(mx, __shfl_xor(mx, d));
  float inv = 1.0f / mx;
#pragma unroll
  for (int r = 0; r < 16; ++r) {
    int row = (r & 3) + 8 * (r >> 2) + 4 * h;
    tmp[pair][row * 33 + j] = D[r] * inv;
  }
  ushort8 w0v, w1v;
#pragma unroll
  for (int e = 0; e < 8; ++e) {
    w0v[e] = f2bf(tmp[pair][j * 33 + h * 16 + e]);
    w1v[e] = f2bf(tmp[pair][j * 33 + h * 16 + 8 + e]);
  }
  *(ushort8*)op = w0v;
  *(ushort8*)(op + 8) = w1v;
  if (l == 0) s1[c] = flog2(mx) + sacc + scs[w + 1];
}

// ---------------------------------------------------------------------------
// K3: final reduce. 16 blocks x 512 (8 waves). Wave w: product of 8 C1 chunks
// -> LDS. Wave 0: product of the 8 LDS mats + alpha0/es(t=0) + NLL.
__global__ __launch_bounds__(512) void k_final2(
    const u16* __restrict__ C1, const float* __restrict__ s1,
    const int* __restrict__ seq, const u16* __restrict__ h2b,
    const u16* __restrict__ E2yT, const float* __restrict__ e2,
    const float* __restrict__ lse2, const float* __restrict__ init_logits,
    float* __restrict__ out) {
  __shared__ u16 mats[8][1024];
  __shared__ float scs[8];
  int b = blockIdx.x;
  int w = threadIdx.x >> 6, l = threadIdx.x & 63;
  int j = l & 31, h = l >> 5;

  float D[16];
  ident_D(j, h, D);
  const u16* base = C1 + ((size_t)b * 64 + w * 8) * 1024;
#pragma unroll
  for (int s = 0; s < 8; ++s) {
    short8 fr0 = *(const short8*)(base + s * 1024 + j * 32 + h * 8);
    short8 fr1 = *(const short8*)(base + s * 1024 + j * 32 + h * 8 + 16);
    mul_step(fr0, fr1, h, D);
  }
  float mx = D[0];
#pragma unroll
  for (int r = 1; r < 16; ++r) mx = fmaxf(mx, D[r]);
#pragma unroll
  for (int d = 1; d < 64; d <<= 1) mx = fmaxf(mx, __shfl_xor(mx, d));
  float inv = 1.0f / mx;
#pragma unroll
  for (int r = 0; r < 16; ++r) {
    int row = (r & 3) + 8 * (r >> 2) + 4 * h;
    mats[w][row * 32 + j] = f2bf(D[r] * inv);
  }
  float si = (l < 8) ? s1[b * 64 + w * 8 + l] : 0.f;
#pragma unroll
  for (int d = 1; d < 64; d <<= 1) si += __shfl_xor(si, d);
  if (l == 0) scs[w] = flog2(mx) + si;
  __syncthreads();

  if (w == 0) {
    float D2[16];
    ident_D(j, h, D2);
#pragma unroll
    for (int s = 0; s < 8; ++s) {
      short8 fr0 = *(const short8*)(&mats[s][j * 32 + h * 8]);
      short8 fr1 = *(const short8*)(&mats[s][j * 32 + h * 8 + 16]);
      mul_step(fr0, fr1, h, D2);
    }
    // es(b, 0, j): input token at t=0 is the start token 0
    int y0 = seq[b * TT];
    float dot = es_dot(E2yT + ((size_t)y0 * KK + j) * HH + h * 64,
                       h2b + h * 64);
    dot += __shfl_xor(dot, 32);
    float esj = (dot + e2[j * VV + y0]) * INV_LN2 - lse2[j];
    // alpha0 (log2 domain)
    float il = init_logits[j] * INV_LN2;
    float m0 = il;
#pragma unroll
    for (int d = 1; d < 32; d <<= 1) m0 = fmaxf(m0, __shfl_xor(m0, d));
    float s0 = fexp2(il - m0);
#pragma unroll
    for (int d = 1; d < 32; d <<= 1) s0 += __shfl_xor(s0, d);
    float lse0 = m0 + flog2(s0);
    float z = il - lse0 + esj;
    float am = z;
#pragma unroll
    for (int d = 1; d < 32; d <<= 1) am = fmaxf(am, __shfl_xor(am, d));
    float a0 = fexp2(z - am);
    float colsum = 0.f;
#pragma unroll
    for (int r = 0; r < 16; ++r) colsum += D2[r];
    float p = a0 * colsum;
#pragma unroll
    for (int d = 1; d < 64; d <<= 1) p += __shfl_xor(p, d);
    float sct = (l < 8) ? scs[l] : 0.f;
#pragma unroll
    for (int d = 1; d < 64; d <<= 1) sct += __shfl_xor(sct, d);
    if (l == 0) out[b] = -LN2 * (flog2(p) + am + sct);
  }
}

// ---------------------------------------------------------------------------
extern "C" void kernel_launch(void* const* d_in, const int* in_sizes, int n_in,
                              void* d_out, int out_size, void* d_ws,
                              size_t ws_size, hipStream_t stream) {
  const int* seq = (const int*)d_in[0];
  const int* lengths = (const int*)d_in[1];
  const float* emb = (const float*)d_in[2];
  const float* W1 = (const float*)d_in[3];
  const float* b1 = (const float*)d_in[4];
  const float* W2 = (const float*)d_in[5];
  const float* b2 = (const float*)d_in[6];
  const float* E1 = (const float*)d_in[7];
  const float* e1 = (const float*)d_in[8];
  const float* E2 = (const float*)d_in[9];
  const float* e2 = (const float*)d_in[10];
  const float* init_logits = (const float*)d_in[11];
  float* out = (float*)d_out;

  char* wsb = (char*)d_ws;
  float* ltrans = (float*)(wsb + 0);         // 2,097,152 B
  u16* h2b = (u16*)(wsb + 2097152);          //   131,072 B
  u16* h1b = (u16*)(wsb + 2228224);          //   131,072 B
  u16* E2bT = (u16*)(wsb + 2359296);         // 4,194,304 B -> 6,553,600
  u16* W2T = (u16*)(wsb + 6553600);          //   262,144 B -> 6,815,744
  float* lse2 = (float*)(wsb + 6815744);     //    65,536 B -> 6,881,280
  u16* C1 = (u16*)(wsb + 6881280);           // 2,097,152 B -> 8,978,432
  float* s1 = (float*)(wsb + 8978432);       //     4,096 B -> 8,982,528
  u16* E2yT = (u16*)(wsb + 8982528);         // 4,194,304 B -> 13,176,832

  k_prep1<<<1120, 256, 0, stream>>>(E2, E2bT, E2yT, W2, W2T, emb, W1, b1, E1,
                                    e1, h1b, h2b);
  k_tables<<<640, 256, 0, stream>>>(h1b, W2T, b2, ltrans, h2b, E2bT, e2, lse2);
  k_matprod<<<256, 512, 0, stream>>>(seq, lengths, ltrans, h2b, E2yT, e2,
                                     lse2, C1, s1);
  k_final2<<<16, 512, 0, stream>>>(C1, s1, seq, h2b, E2yT, e2, lse2,
                                   init_logits, out);
}